// Round 4
// baseline (4260.572 us; speedup 1.0000x reference)
//
#include <hip/hip_runtime.h>
#include <hip/hip_bf16.h>

// GraphLSTM: B=128, S=128, N=24, F=16, H=32 -> IS=384, HS=768, gates=3072.
// Inputs (FP32): x[128,128,24,16], h0[128,24,32], c0[128,24,32],
//                W[384,3072], U[768,3072], bias[3072], G[24,24]
// Output (FP32): hidden_seq[128,128,768] ++ h[128,768] ++ c[128,768]
// Internally: masked weights + MFMA operands in bf16, accumulation fp32.

typedef __bf16 bf16x8 __attribute__((ext_vector_type(8)));
typedef float f32x4 __attribute__((ext_vector_type(4)));

#define HS 768
#define GATES 3072
#define KV 1152          // combined K: 384 (W) + 768 (U)
#define SEQ 128
#define BATCH 128
#define OUT_HID (BATCH*SEQ*HS)
#define CP 72            // LDS chunk pitch (64 + 8 pad): breaks bank conflicts

__device__ __forceinline__ float fast_sig(float x) {
    return 1.0f / (1.0f + __expf(-x));
}
__device__ __forceinline__ float fast_tanh(float x) {
    x = fminf(fmaxf(x, -15.0f), 15.0f);
    float e = __expf(2.0f * x);
    return (e - 1.0f) / (e + 1.0f);
}

// convert 8 consecutive fp32 -> bf16x8, store to LDS (16B)
__device__ __forceinline__ void stage8(__bf16* dst, const float* src) {
    float4 v0 = *(const float4*)src;
    float4 v1 = *(const float4*)(src + 4);
    bf16x8 p;
    p[0] = (__bf16)v0.x; p[1] = (__bf16)v0.y; p[2] = (__bf16)v0.z; p[3] = (__bf16)v0.w;
    p[4] = (__bf16)v1.x; p[5] = (__bf16)v1.y; p[6] = (__bf16)v1.z; p[7] = (__bf16)v1.w;
    *(bf16x8*)dst = p;
}

// ---------------------------------------------------------------------------
// Kernel 1: masked + transposed weights (fp32 in, bf16 out).
// VmT[c][k] = (k<384 ? W[k][c]*G[k/16][(c%768)/32]
//                    : U[k-384][c]*G[(k-384)/32][(c%768)/32])
// ---------------------------------------------------------------------------
__global__ void prep_kernel(const float* __restrict__ W, const float* __restrict__ U,
                            const float* __restrict__ G, __bf16* __restrict__ VmT) {
    __shared__ __bf16 tile[64][65];
    const int kvb = blockIdx.x * 64;   // 18 blocks
    const int cb  = blockIdx.y * 64;   // 48 blocks
    const int tid = threadIdx.x;
    {
        const int cl = tid & 63, kl0 = tid >> 6;
        #pragma unroll
        for (int i = 0; i < 16; ++i) {
            int kl = kl0 + i * 4;
            int kv = kvb + kl;
            int c  = cb + cl;
            int nout = (c % HS) >> 5;           // output node of this gate col
            float g, v;
            if (kv < 384) {
                g = G[(kv >> 4) * 24 + nout];
                v = W[(size_t)kv * GATES + c];
            } else {
                int ku = kv - 384;
                g = G[(ku >> 5) * 24 + nout];
                v = U[(size_t)ku * GATES + c];
            }
            tile[kl][cl] = (__bf16)(v * g);
        }
    }
    __syncthreads();
    {
        const int kl = tid & 63, cl0 = tid >> 6;
        #pragma unroll
        for (int i = 0; i < 16; ++i) {
            int c = cl0 + i * 4;
            VmT[(size_t)(cb + c) * KV + kvb + kl] = tile[kl][c];
        }
    }
}

// ---------------------------------------------------------------------------
// Kernel 2: ONE timestep. 24 blocks x 256 threads.
// Block bx owns hidden cols j in [bx*32, bx*32+32) across all 4 gates:
// A-rows ri = gate + 4*jj  (cg = (ri&3)*768 + jb + (ri>>2))  -> the MFMA
// C/D layout (row = quad*4 + r, col = m) makes reg r == gate r (i,f,g,o),
// j = jb + mt*4 + quad, b = w*32 + nt*16 + m  -- all lane-local.
// K = 1152 streamed in 18 chunks of 64 through LDS (fp32->bf16 on stage).
// h exchange across steps goes through d_out (kernel-boundary coherence).
// Cell state carried in f32 workspace.
// ---------------------------------------------------------------------------
__global__ __launch_bounds__(256) void step_kernel(
        const float* __restrict__ xptr,    // x + t*384  (row stride SEQ*384)
        const float* hptr,                 // h0 (t==0) or out + (t-1)*768
        const float* __restrict__ c0,      // initial cell (read when first)
        float* __restrict__ cstate,        // f32 [128*768] carried cell state
        const __bf16* __restrict__ VmT,    // [3072][1152] bf16
        const float* __restrict__ bias,    // [3072]
        float* out,                        // full output base (fp32)
        long hstride, int t, int first, int last) {
    __shared__ __align__(16) __bf16 As[128 * CP];
    __shared__ __align__(16) __bf16 Bs[128 * CP];
    const int tid = threadIdx.x;
    const int lane = tid & 63, w = tid >> 6;
    const int m = lane & 15, quad = lane >> 4;
    const int jb = blockIdx.x * 32;

    // accumulators init with bias (gate r at reg r)
    f32x4 acc[8][2];
    #pragma unroll
    for (int mt = 0; mt < 8; ++mt) {
        #pragma unroll
        for (int r = 0; r < 4; ++r) {
            float bv = bias[r * HS + jb + mt * 4 + quad];
            acc[mt][0][r] = bv;
            acc[mt][1][r] = bv;
        }
    }

    for (int s = 0; s < 18; ++s) {
        const int kb = s * 64;
        // stage A chunk: 128 interleaved c-rows x 64 k (bf16 copy)
        #pragma unroll
        for (int i = 0; i < 4; ++i) {
            int ch = tid + i * 256;
            int ri = ch >> 3, ko = (ch & 7) * 8;
            int cg = (ri & 3) * HS + jb + (ri >> 2);
            *(uint4*)&As[ri * CP + ko] = *(const uint4*)&VmT[(size_t)cg * KV + kb + ko];
        }
        // stage B chunk: 128 batch rows x 64 k (fp32 -> bf16)
        #pragma unroll
        for (int i = 0; i < 4; ++i) {
            int ch = tid + i * 256;
            int b = ch >> 3, ko = (ch & 7) * 8;
            const float* src;
            if (kb < 384) src = xptr + (size_t)b * (SEQ * 384) + kb + ko;
            else          src = hptr + (size_t)b * hstride + (kb - 384) + ko;
            stage8(&Bs[b * CP + ko], src);
        }
        __syncthreads();
        #pragma unroll
        for (int kk = 0; kk < 2; ++kk) {
            bf16x8 bfrag[2];
            #pragma unroll
            for (int nt = 0; nt < 2; ++nt)
                bfrag[nt] = *(const bf16x8*)&Bs[(w * 32 + nt * 16 + m) * CP + kk * 32 + quad * 8];
            #pragma unroll
            for (int mt = 0; mt < 8; ++mt) {
                bf16x8 a = *(const bf16x8*)&As[(mt * 16 + m) * CP + kk * 32 + quad * 8];
                #pragma unroll
                for (int nt = 0; nt < 2; ++nt)
                    acc[mt][nt] = __builtin_amdgcn_mfma_f32_16x16x32_bf16(a, bfrag[nt], acc[mt][nt], 0, 0, 0);
            }
        }
        __syncthreads();
    }

    // LSTM elementwise + stores (lane-local gates: acc reg index == gate)
    #pragma unroll
    for (int mt = 0; mt < 8; ++mt) {
        const int j = jb + mt * 4 + quad;
        #pragma unroll
        for (int nt = 0; nt < 2; ++nt) {
            const int b = w * 32 + nt * 16 + m;
            float cp = first ? c0[b * HS + j] : cstate[b * HS + j];
            float ii = fast_sig(acc[mt][nt][0]);
            float ff = fast_sig(acc[mt][nt][1]);
            float gg = fast_tanh(acc[mt][nt][2]);
            float oo = fast_sig(acc[mt][nt][3]);
            float cn = ff * cp + ii * gg;
            float hn = oo * fast_tanh(cn);
            cstate[b * HS + j] = cn;
            out[((size_t)b * SEQ + t) * HS + j] = hn;
            if (last) {
                out[OUT_HID + b * HS + j] = hn;
                out[OUT_HID + BATCH * HS + b * HS + j] = cn;
            }
        }
    }
}

// ---------------------------------------------------------------------------
extern "C" void kernel_launch(void* const* d_in, const int* in_sizes, int n_in,
                              void* d_out, int out_size, void* d_ws, size_t ws_size,
                              hipStream_t stream) {
    (void)in_sizes; (void)n_in; (void)out_size; (void)ws_size;
    const float* x    = (const float*)d_in[0];
    const float* h0   = (const float*)d_in[1];
    const float* c0   = (const float*)d_in[2];
    const float* W    = (const float*)d_in[3];
    const float* U    = (const float*)d_in[4];
    const float* bias = (const float*)d_in[5];
    const float* G    = (const float*)d_in[6];
    float* out = (float*)d_out;

    __bf16* VmT   = (__bf16*)d_ws;                                   // 6.75 MB
    float* cstate = (float*)((char*)d_ws + (size_t)GATES * KV * 2);  // 384 KB

    prep_kernel<<<dim3(18, 48), 256, 0, stream>>>(W, U, G, VmT);

    for (int t = 0; t < SEQ; ++t) {
        const float* xptr = x + (size_t)t * 384;
        const float* hptr = (t == 0) ? h0 : out + (size_t)(t - 1) * HS;
        long hstride = (t == 0) ? (long)HS : (long)SEQ * HS;
        step_kernel<<<dim3(24), dim3(256), 0, stream>>>(
            xptr, hptr, c0, cstate, VmT, bias, out,
            hstride, t, (t == 0) ? 1 : 0, (t == SEQ - 1) ? 1 : 0);
    }
}

// Round 5
// 1708.779 us; speedup vs baseline: 2.4933x; 2.4933x over previous
//
#include <hip/hip_runtime.h>
#include <hip/hip_bf16.h>

// GraphLSTM: B=128, S=128, N=24, F=16, H=32 -> IS=384, HS=768, gates=3072.
// Inputs (FP32): x[128,128,24,16], h0[128,24,32], c0[128,24,32],
//                W[384,3072], U[768,3072], bias[3072], G[24,24]
// Output (FP32): hidden_seq[128,128,768] ++ h[128,768] ++ c[128,768]
// Internals: masked weights + MFMA operands bf16, fp32 accumulate.

typedef __bf16 bf16x8 __attribute__((ext_vector_type(8)));
typedef float f32x4 __attribute__((ext_vector_type(4)));

#define HS 768
#define GATES 3072
#define KV 1152          // combined K: 384 (W) + 768 (U)
#define SEQ 128
#define BATCH 128
#define OUT_HID (BATCH*SEQ*HS)
#define BPITCH 1160      // LDS row pitch: 145 uint4/row (odd) -> free 2-way only

__device__ __forceinline__ float fast_sig(float x) {
    return 1.0f / (1.0f + __expf(-x));
}
__device__ __forceinline__ float fast_tanh(float x) {
    x = fminf(fmaxf(x, -15.0f), 15.0f);
    float e = __expf(2.0f * x);
    return (e - 1.0f) / (e + 1.0f);
}

// convert 8 consecutive fp32 -> bf16x8, store 16B
__device__ __forceinline__ void stage8(__bf16* dst, const float* src) {
    float4 v0 = *(const float4*)src;
    float4 v1 = *(const float4*)(src + 4);
    bf16x8 p;
    p[0] = (__bf16)v0.x; p[1] = (__bf16)v0.y; p[2] = (__bf16)v0.z; p[3] = (__bf16)v0.w;
    p[4] = (__bf16)v1.x; p[5] = (__bf16)v1.y; p[6] = (__bf16)v1.z; p[7] = (__bf16)v1.w;
    *(bf16x8*)dst = p;
}

// ---------------------------------------------------------------------------
// Kernel 1: masked + transposed weights (fp32 in, bf16 out).   [R4-validated]
// VmT[c][k] = (k<384 ? W[k][c]*G[k/16][(c%768)/32]
//                    : U[k-384][c]*G[(k-384)/32][(c%768)/32])
// ---------------------------------------------------------------------------
__global__ void prep_kernel(const float* __restrict__ W, const float* __restrict__ U,
                            const float* __restrict__ G, __bf16* __restrict__ VmT) {
    __shared__ __bf16 tile[64][65];
    const int kvb = blockIdx.x * 64;   // 18 blocks
    const int cb  = blockIdx.y * 64;   // 48 blocks
    const int tid = threadIdx.x;
    {
        const int cl = tid & 63, kl0 = tid >> 6;
        #pragma unroll
        for (int i = 0; i < 16; ++i) {
            int kl = kl0 + i * 4;
            int kv = kvb + kl;
            int c  = cb + cl;
            int nout = (c % HS) >> 5;
            float g, v;
            if (kv < 384) {
                g = G[(kv >> 4) * 24 + nout];
                v = W[(size_t)kv * GATES + c];
            } else {
                int ku = kv - 384;
                g = G[(ku >> 5) * 24 + nout];
                v = U[(size_t)ku * GATES + c];
            }
            tile[kl][cl] = (__bf16)(v * g);
        }
    }
    __syncthreads();
    {
        const int kl = tid & 63, cl0 = tid >> 6;
        #pragma unroll
        for (int i = 0; i < 16; ++i) {
            int c = cl0 + i * 4;
            VmT[(size_t)(cb + c) * KV + kvb + kl] = tile[kl][c];
        }
    }
}

// ---------------------------------------------------------------------------
// Kernel 2: x fp32 [b][t][384] -> bf16 [t][b][384]
// ---------------------------------------------------------------------------
__global__ void prep_x(const float* __restrict__ x, __bf16* __restrict__ xb) {
    const int g = blockIdx.x * 256 + threadIdx.x;      // 3072 * 256 chunks of 8
    const int e = g * 8;
    const int b = e / (SEQ * 384);
    const int rem = e - b * (SEQ * 384);
    const int t = rem / 384;
    const int k = rem - t * 384;
    float4 v0 = *(const float4*)&x[e];
    float4 v1 = *(const float4*)&x[e + 4];
    bf16x8 p;
    p[0] = (__bf16)v0.x; p[1] = (__bf16)v0.y; p[2] = (__bf16)v0.z; p[3] = (__bf16)v0.w;
    p[4] = (__bf16)v1.x; p[5] = (__bf16)v1.y; p[6] = (__bf16)v1.z; p[7] = (__bf16)v1.w;
    *(bf16x8*)&xb[((size_t)t * BATCH + b) * 384 + k] = p;
}

// ---------------------------------------------------------------------------
// Kernel 3: persistent recurrent scan, non-recurrent term fused (K=1152).
// 8 teams (16 batch rows) x 24 WGs = 192 WGs, 1 WG/CU (VGPR-forced), all
// co-resident. Wave owns 8 hidden cols x 4 gates; W||U weights in 288 VGPRs.
// Tile T A-rows: cg = (m&3)*768 + jbase + T*4 + (m>>2)  [R4-validated algebra]
// -> C/D reg r == gate r; j = jbase + T*4 + quad; b = bbase + m. Per step:
// stage [x_t ; h_{t-1}] 16x1152 bf16 in LDS, 72 MFMAs, lane-local LSTM,
// fp32 h -> out, bf16 h -> double-buffered exchange, team barrier + fences.
// ---------------------------------------------------------------------------
__global__ __launch_bounds__(256, 1) void scan_kernel(
        const __bf16* __restrict__ xb,     // [t][b][384] bf16
        const float* __restrict__ h0,
        const float* __restrict__ c0,
        const __bf16* __restrict__ VmT,    // [3072][1152] bf16
        const float* __restrict__ bias,
        float* out,
        __bf16* xh,                        // [2][128][768] bf16 h-exchange
        unsigned* bar) {
    __shared__ __align__(16) __bf16 Bs[16 * BPITCH];
    const int tid = threadIdx.x;
    const int lane = tid & 63, wv = tid >> 6;
    const int m = lane & 15, quad = lane >> 4;
    const int team = blockIdx.x & 7, wg = blockIdx.x >> 3;   // XCD-local teams
    const int bbase = team * 16;
    const int jbase = wg * 32 + wv * 8;

    // --- weights -> 288 VGPRs (read VmT exactly once for the whole scan) ---
    bf16x8 w[2][36];
    #pragma unroll
    for (int T = 0; T < 2; ++T) {
        const int cg = (m & 3) * HS + jbase + T * 4 + (m >> 2);
        const __bf16* wp = VmT + (size_t)cg * KV;
        #pragma unroll
        for (int kk = 0; kk < 36; ++kk)
            w[T][kk] = *(const bf16x8*)(wp + kk * 32 + quad * 8);
    }

    const int b_own = bbase + m;
    const int j0 = jbase + quad;
    const int j1 = jbase + 4 + quad;
    float cv0 = c0[b_own * HS + j0];
    float cv1 = c0[b_own * HS + j1];
    f32x4 bias0, bias1;
    #pragma unroll
    for (int r = 0; r < 4; ++r) {
        bias0[r] = bias[r * HS + j0];
        bias1[r] = bias[r * HS + j1];
    }

    unsigned* cnt = bar + team * 64;
    unsigned* flg = cnt + 32;

    #pragma unroll 1
    for (int t = 0; t < SEQ; ++t) {
        // stage [x_t ; h_{t-1}] for this team's 16 batches: 2304 uint4
        #pragma unroll
        for (int i = 0; i < 9; ++i) {
            int ch = tid + i * 256;
            if (ch < 768) {                      // x: 16 rows x 48 uint4
                int row = ch / 48, ko = (ch % 48) * 8;
                *(uint4*)&Bs[row * BPITCH + ko] =
                    *(const uint4*)&xb[((size_t)t * BATCH + bbase + row) * 384 + ko];
            } else {                             // h: 16 rows x 96 uint4
                int c2 = ch - 768;
                int row = c2 / 96, ko = (c2 % 96) * 8;
                if (t == 0)
                    stage8(&Bs[row * BPITCH + 384 + ko],
                           &h0[(size_t)(bbase + row) * HS + ko]);
                else
                    *(uint4*)&Bs[row * BPITCH + 384 + ko] =
                        *(const uint4*)&xh[(((size_t)((t - 1) & 1)) * BATCH + bbase + row) * HS + ko];
            }
        }
        __syncthreads();

        // gates = bias + [x_t ; h_{t-1}] @ [Wm ; Um]
        f32x4 acc0 = bias0, acc1 = bias1;
        #pragma unroll
        for (int kk = 0; kk < 36; ++kk) {
            bf16x8 bf = *(const bf16x8*)&Bs[m * BPITCH + kk * 32 + quad * 8];
            acc0 = __builtin_amdgcn_mfma_f32_16x16x32_bf16(w[0][kk], bf, acc0, 0, 0, 0);
            acc1 = __builtin_amdgcn_mfma_f32_16x16x32_bf16(w[1][kk], bf, acc1, 0, 0, 0);
        }

        // LSTM elementwise (lane-local: acc reg index == gate i,f,g,o)
        float h0v, h1v;
        {
            float ii = fast_sig(acc0[0]), ff = fast_sig(acc0[1]);
            float gg = fast_tanh(acc0[2]), oo = fast_sig(acc0[3]);
            cv0 = ff * cv0 + ii * gg;
            h0v = oo * fast_tanh(cv0);
        }
        {
            float ii = fast_sig(acc1[0]), ff = fast_sig(acc1[1]);
            float gg = fast_tanh(acc1[2]), oo = fast_sig(acc1[3]);
            cv1 = ff * cv1 + ii * gg;
            h1v = oo * fast_tanh(cv1);
        }

        const size_t obase = ((size_t)b_own * SEQ + t) * HS;
        out[obase + j0] = h0v;
        out[obase + j1] = h1v;
        {   // bf16 h -> exchange buffer (double-buffered)
            __bf16* xw = xh + ((size_t)(t & 1) * BATCH + b_own) * HS;
            xw[j0] = (__bf16)h0v;
            xw[j1] = (__bf16)h1v;
        }
        if (t == SEQ - 1) {
            out[OUT_HID + b_own * HS + j0] = h0v;
            out[OUT_HID + b_own * HS + j1] = h1v;
            out[OUT_HID + BATCH * HS + b_own * HS + j0] = cv0;
            out[OUT_HID + BATCH * HS + b_own * HS + j1] = cv1;
        }

        if (t < SEQ - 1) {
            __syncthreads();               // drains vmcnt before s_barrier
            if (tid == 0) {
                __threadfence();           // release: cross-XCD visibility
                unsigned old = __hip_atomic_fetch_add(cnt, 1u, __ATOMIC_RELAXED,
                                                      __HIP_MEMORY_SCOPE_AGENT);
                if (old == (unsigned)(t * 24 + 23)) {
                    __hip_atomic_store(flg, (unsigned)(t + 1), __ATOMIC_RELEASE,
                                       __HIP_MEMORY_SCOPE_AGENT);
                } else {
                    while (__hip_atomic_load(flg, __ATOMIC_RELAXED,
                                             __HIP_MEMORY_SCOPE_AGENT) < (unsigned)(t + 1)) {
                        __builtin_amdgcn_s_sleep(2);
                    }
                }
                __threadfence();           // acquire: invalidate stale caches
            }
            __syncthreads();
        }
    }
}

// ---------------------------------------------------------------------------
extern "C" void kernel_launch(void* const* d_in, const int* in_sizes, int n_in,
                              void* d_out, int out_size, void* d_ws, size_t ws_size,
                              hipStream_t stream) {
    (void)in_sizes; (void)n_in; (void)out_size; (void)ws_size;
    const float* x    = (const float*)d_in[0];
    const float* h0   = (const float*)d_in[1];
    const float* c0   = (const float*)d_in[2];
    const float* W    = (const float*)d_in[3];
    const float* U    = (const float*)d_in[4];
    const float* bias = (const float*)d_in[5];
    const float* G    = (const float*)d_in[6];
    float* out = (float*)d_out;

    char* wsb = (char*)d_ws;
    unsigned* bar = (unsigned*)wsb;                                  // 4 KB
    __bf16* VmT = (__bf16*)(wsb + 4096);                             // 6.75 MB
    __bf16* xb  = (__bf16*)(wsb + 4096 + (size_t)GATES * KV * 2);    // 12.6 MB
    __bf16* xh  = (__bf16*)(wsb + 4096 + (size_t)GATES * KV * 2
                                 + (size_t)SEQ * BATCH * 384 * 2);   // 393 KB

    hipMemsetAsync(bar, 0, 4096, stream);
    prep_kernel<<<dim3(18, 48), 256, 0, stream>>>(W, U, G, VmT);
    prep_x<<<dim3(3072), 256, 0, stream>>>(x, xb);
    scan_kernel<<<dim3(192), dim3(256), 0, stream>>>(xb, h0, c0, VmT, bias,
                                                     out, xh, bar);
}

// Round 8
// 642.362 us; speedup vs baseline: 6.6327x; 2.6601x over previous
//
#include <hip/hip_runtime.h>
#include <hip/hip_bf16.h>

// GraphLSTM: B=128, S=128, N=24, F=16, H=32 -> IS=384, HS=768, gates=3072.
// Inputs (FP32): x[128,128,24,16], h0[128,24,32], c0[128,24,32],
//                W[384,3072], U[768,3072], bias[3072], G[24,24]
// Output (FP32): hidden_seq[128,128,768] ++ h[128,768] ++ c[128,768]
// Internals: masked weights + MFMA operands bf16, fp32 accumulate.
// Cross-WG h exchange: packed u32, producer atomic-exchange RMW, consumer
// relaxed atomic loads. R6/R7 failure was NOT coherence: the consumer only
// loaded 1536 of 6144 u32 (cols 192..767 frozen at h0) -- fixed here.

typedef __bf16 bf16x8 __attribute__((ext_vector_type(8)));
typedef float f32x4 __attribute__((ext_vector_type(4)));

#define HS 768
#define GATES 3072
#define KV 1152          // combined K: 384 (W) + 768 (U)
#define SEQ 128
#define BATCH 128
#define OUT_HID (BATCH*SEQ*HS)
#define BPITCH 1160      // LDS row pitch (elems); rows 16B aligned

__device__ __forceinline__ float fast_sig(float x) {
    return 1.0f / (1.0f + __expf(-x));
}
__device__ __forceinline__ float fast_tanh(float x) {
    x = fminf(fmaxf(x, -15.0f), 15.0f);
    float e = __expf(2.0f * x);
    return (e - 1.0f) / (e + 1.0f);
}

// convert 8 consecutive fp32 -> bf16x8 (RNE via cast)
__device__ __forceinline__ bf16x8 cvt8(const float* src) {
    float4 v0 = *(const float4*)src;
    float4 v1 = *(const float4*)(src + 4);
    bf16x8 p;
    p[0] = (__bf16)v0.x; p[1] = (__bf16)v0.y; p[2] = (__bf16)v0.z; p[3] = (__bf16)v0.w;
    p[4] = (__bf16)v1.x; p[5] = (__bf16)v1.y; p[6] = (__bf16)v1.z; p[7] = (__bf16)v1.w;
    return p;
}

// k-chunk swizzle: breaks the 8-way LDS bank conflict of row-strided reads
__device__ __forceinline__ int swz(int c8, int row) {
    return (c8 & ~3) | ((c8 & 3) ^ (row & 3));
}

// ---------------------------------------------------------------------------
// Kernel 1: masked + transposed weights (fp32 in, bf16 out).   [R4-validated]
// VmT[c][k] = (k<384 ? W[k][c]*G[k/16][(c%768)/32]
//                    : U[k-384][c]*G[(k-384)/32][(c%768)/32])
// ---------------------------------------------------------------------------
__global__ void prep_kernel(const float* __restrict__ W, const float* __restrict__ U,
                            const float* __restrict__ G, __bf16* __restrict__ VmT) {
    __shared__ __bf16 tile[64][65];
    const int kvb = blockIdx.x * 64;
    const int cb  = blockIdx.y * 64;
    const int tid = threadIdx.x;
    {
        const int cl = tid & 63, kl0 = tid >> 6;
        #pragma unroll
        for (int i = 0; i < 16; ++i) {
            int kl = kl0 + i * 4;
            int kv = kvb + kl;
            int c  = cb + cl;
            int nout = (c % HS) >> 5;
            float g, v;
            if (kv < 384) {
                g = G[(kv >> 4) * 24 + nout];
                v = W[(size_t)kv * GATES + c];
            } else {
                int ku = kv - 384;
                g = G[(ku >> 5) * 24 + nout];
                v = U[(size_t)ku * GATES + c];
            }
            tile[kl][cl] = (__bf16)(v * g);
        }
    }
    __syncthreads();
    {
        const int kl = tid & 63, cl0 = tid >> 6;
        #pragma unroll
        for (int i = 0; i < 16; ++i) {
            int c = cl0 + i * 4;
            VmT[(size_t)(cb + c) * KV + kvb + kl] = tile[kl][c];
        }
    }
}

// ---------------------------------------------------------------------------
// Kernel 2: x fp32 [b][t][384] -> bf16 [t][b][384]
// ---------------------------------------------------------------------------
__global__ void prep_x(const float* __restrict__ x, __bf16* __restrict__ xb) {
    const int g = blockIdx.x * 256 + threadIdx.x;
    const int e = g * 8;
    const int b = e / (SEQ * 384);
    const int rem = e - b * (SEQ * 384);
    const int t = rem / 384;
    const int k = rem - t * 384;
    *(bf16x8*)&xb[((size_t)t * BATCH + b) * 384 + k] = cvt8(&x[e]);
}

// ---------------------------------------------------------------------------
// Kernel 3: persistent scan. 8 teams x 24 WGs = 192 WGs, 1 WG/CU.
// Wave owns 8 adjacent hidden cols x 4 gates; weights in 288 regs.
// A-row m -> weight col cg = (m&3)*768 + jbase + 2*(m>>2) + T, so lane
// (quad,m) holds gates r=0..3 of j0 = jbase+2*quad (T=0) and j1 = j0+1
// (T=1): the (h[j0],h[j1]) pair packs into one u32 for coherent exchange.
// Per step: MFMA(72) -> LSTM -> fp32 out + u32 atomicExch h -> syncthreads
// (drains vmcnt) -> stage x_{t+1} -> tid0 RMW-add + poll cnt >= 24(t+1) ->
// stage h_t via 24 coherent u32 loads/thread (FULL 6144) -> syncthreads.
// ---------------------------------------------------------------------------
__global__ __launch_bounds__(256, 1) void scan_kernel(
        const __bf16* __restrict__ xb,     // [t][b][384] bf16
        const float* __restrict__ h0,
        const float* __restrict__ c0,
        const __bf16* __restrict__ VmT,    // [3072][1152] bf16
        const float* __restrict__ bias,
        float* out,
        unsigned* xh32,                    // [2][128][384] packed bf16 pairs
        unsigned* bar) {
    __shared__ __align__(16) __bf16 Bs[16 * BPITCH];
    const int tid = threadIdx.x;
    const int lane = tid & 63, wv = tid >> 6;
    const int m = lane & 15, quad = lane >> 4;
    const int team = blockIdx.x & 7, wg = blockIdx.x >> 3;
    const int bbase = team * 16;
    const int jbase = wg * 32 + wv * 8;

    // --- weights -> registers (read VmT exactly once for the whole scan) ---
    bf16x8 w[2][36];
    #pragma unroll
    for (int T = 0; T < 2; ++T) {
        const int cg = (m & 3) * HS + jbase + 2 * (m >> 2) + T;
        const __bf16* wp = VmT + (size_t)cg * KV;
        #pragma unroll
        for (int kk = 0; kk < 36; ++kk)
            w[T][kk] = *(const bf16x8*)(wp + kk * 32 + quad * 8);
    }

    const int b_own = bbase + m;
    const int j0 = jbase + 2 * quad;       // even
    const int j1 = j0 + 1;                 // odd (adjacent -> one u32)
    float cv0 = c0[b_own * HS + j0];
    float cv1 = c0[b_own * HS + j1];
    f32x4 bias0, bias1;
    #pragma unroll
    for (int r = 0; r < 4; ++r) {
        bias0[r] = bias[r * HS + j0];
        bias1[r] = bias[r * HS + j1];
    }

    unsigned* cnt = bar + team * 64;
    const int bq = (quad ^ (m & 3));       // per-lane swizzled quad (B-frag)

    // --- pre-loop staging: x_0 (swizzled) + h0 (fp32 -> bf16, swizzled) ---
    #pragma unroll
    for (int i = 0; i < 3; ++i) {
        int ch = tid + i * 256;            // 768 x-chunks
        int row = ch / 48, c8 = ch % 48;
        *(uint4*)&Bs[row * BPITCH + swz(c8, row) * 8] =
            *(const uint4*)&xb[((size_t)0 * BATCH + bbase + row) * 384 + c8 * 8];
    }
    #pragma unroll
    for (int i = 0; i < 6; ++i) {
        int ch = tid + i * 256;            // 1536 h-chunks (bf16x8)
        int row = ch / 96, c8h = ch % 96;
        bf16x8 p = cvt8(&h0[(size_t)(bbase + row) * HS + c8h * 8]);
        *(bf16x8*)&Bs[row * BPITCH + (48 + swz(c8h, row)) * 8] = p;
    }
    __syncthreads();

    #pragma unroll 1
    for (int t = 0; t < SEQ; ++t) {
        // gates = bias + [x_t ; h_{t-1}] @ [Wm ; Um]
        f32x4 acc0 = bias0, acc1 = bias1;
        #pragma unroll
        for (int kk = 0; kk < 36; ++kk) {
            bf16x8 bf = *(const bf16x8*)&Bs[m * BPITCH + kk * 32 + bq * 8];
            acc0 = __builtin_amdgcn_mfma_f32_16x16x32_bf16(w[0][kk], bf, acc0, 0, 0, 0);
            acc1 = __builtin_amdgcn_mfma_f32_16x16x32_bf16(w[1][kk], bf, acc1, 0, 0, 0);
        }

        // LSTM elementwise (lane-local: acc reg index == gate i,f,g,o)
        float h0v, h1v;
        {
            float ii = fast_sig(acc0[0]), ff = fast_sig(acc0[1]);
            float gg = fast_tanh(acc0[2]), oo = fast_sig(acc0[3]);
            cv0 = ff * cv0 + ii * gg;
            h0v = oo * fast_tanh(cv0);
        }
        {
            float ii = fast_sig(acc1[0]), ff = fast_sig(acc1[1]);
            float gg = fast_tanh(acc1[2]), oo = fast_sig(acc1[3]);
            cv1 = ff * cv1 + ii * gg;
            h1v = oo * fast_tanh(cv1);
        }

        const size_t obase = ((size_t)b_own * SEQ + t) * HS;
        out[obase + j0] = h0v;
        out[obase + j1] = h1v;

        if (t == SEQ - 1) {
            out[OUT_HID + b_own * HS + j0] = h0v;
            out[OUT_HID + b_own * HS + j1] = h1v;
            out[OUT_HID + BATCH * HS + b_own * HS + j0] = cv0;
            out[OUT_HID + BATCH * HS + b_own * HS + j1] = cv1;
            break;
        }

        // packed bf16 pair -> exchange (atomic RMW: known coherent path)
        {
            unsigned lo = (unsigned)__builtin_bit_cast(unsigned short, (__bf16)h0v);
            unsigned hi = (unsigned)__builtin_bit_cast(unsigned short, (__bf16)h1v);
            unsigned* dst = xh32 + ((size_t)(t & 1) * BATCH + b_own) * 384
                                 + (jbase >> 1) + quad;
            (void)__hip_atomic_exchange(dst, lo | (hi << 16), __ATOMIC_RELAXED,
                                        __HIP_MEMORY_SCOPE_AGENT);
        }

        __syncthreads();   // LDS free + every wave's RMWs vmcnt-drained

        // stage x_{t+1} (no cross-WG dependency -> before the team barrier)
        #pragma unroll
        for (int i = 0; i < 3; ++i) {
            int ch = tid + i * 256;
            int row = ch / 48, c8 = ch % 48;
            *(uint4*)&Bs[row * BPITCH + swz(c8, row) * 8] =
                *(const uint4*)&xb[((size_t)(t + 1) * BATCH + bbase + row) * 384 + c8 * 8];
        }

        // team barrier: arrival count, monotone target 24*(t+1)
        if (tid == 0) {
            __hip_atomic_fetch_add(cnt, 1u, __ATOMIC_RELAXED,
                                   __HIP_MEMORY_SCOPE_AGENT);
            while (__hip_atomic_load(cnt, __ATOMIC_RELAXED,
                                     __HIP_MEMORY_SCOPE_AGENT) < (unsigned)(24 * (t + 1))) {
                __builtin_amdgcn_s_sleep(1);
            }
        }
        __syncthreads();

        // stage h_t: FULL 16 rows x 384 u32 = 6144 (24 per thread)
        {
            const unsigned* src = xh32 + (size_t)(t & 1) * BATCH * 384;
            unsigned vals[24];
            #pragma unroll
            for (int i = 0; i < 24; ++i) {
                int ch = tid + i * 256;            // 0..6143
                int row = ch / 384, u = ch % 384;
                vals[i] = __hip_atomic_load(&src[(size_t)(bbase + row) * 384 + u],
                                            __ATOMIC_RELAXED, __HIP_MEMORY_SCOPE_AGENT);
            }
            #pragma unroll
            for (int i = 0; i < 24; ++i) {
                int ch = tid + i * 256;
                int row = ch / 384, u = ch % 384;
                int c8h = u >> 2;                  // h-region chunk (8 elems)
                int eo = (u & 3) * 2;              // elem offset within chunk
                *(unsigned*)&Bs[row * BPITCH + (48 + swz(c8h, row)) * 8 + eo] = vals[i];
            }
        }
        __syncthreads();
    }
}

// ---------------------------------------------------------------------------
extern "C" void kernel_launch(void* const* d_in, const int* in_sizes, int n_in,
                              void* d_out, int out_size, void* d_ws, size_t ws_size,
                              hipStream_t stream) {
    (void)in_sizes; (void)n_in; (void)out_size; (void)ws_size;
    const float* x    = (const float*)d_in[0];
    const float* h0   = (const float*)d_in[1];
    const float* c0   = (const float*)d_in[2];
    const float* W    = (const float*)d_in[3];
    const float* U    = (const float*)d_in[4];
    const float* bias = (const float*)d_in[5];
    const float* G    = (const float*)d_in[6];
    float* out = (float*)d_out;

    char* wsb = (char*)d_ws;
    unsigned* bar = (unsigned*)wsb;                                   // 4 KB
    __bf16* VmT  = (__bf16*)(wsb + 4096);                             // 6.75 MB
    __bf16* xb   = (__bf16*)(wsb + 4096 + (size_t)GATES * KV * 2);    // 12.6 MB
    unsigned* xh32 = (unsigned*)(wsb + 4096 + (size_t)GATES * KV * 2
                                      + (size_t)SEQ * BATCH * 384 * 2);  // 393 KB

    hipMemsetAsync(bar, 0, 4096, stream);
    prep_kernel<<<dim3(18, 48), 256, 0, stream>>>(W, U, G, VmT);
    prep_x<<<dim3(3072), 256, 0, stream>>>(x, xb);
    scan_kernel<<<dim3(192), dim3(256), 0, stream>>>(xb, h0, c0, VmT, bias,
                                                     out, xh32, bar);
}